// Round 7
// baseline (51.964 us; speedup 1.0000x reference)
//
#include <hip/hip_runtime.h>

#define N_IN_   1024
#define N_OUT_  1536
#define N_CH    16
#define TY      6       // output rows per block tile (6 | 768: never straddles ifftshift wrap)
#define XT      256     // output cols per block tile (256 | 768)
#define XW      64      // staged input x-window (max span 57+5 < 64)
#define CPB     4       // channels per block

// Catmull-Rom-style cubic kernel, matching the reference formula in f32.
// Exact 0 for |x| >= 2 -> widened tap windows are formula-identical.
__device__ __forceinline__ float cubic_w(float x) {
    float ax = fabsf(x);
    float f1 = 1.0f + ax * ax * (1.5f * ax - 2.5f);
    float t  = 2.0f - ax;
    float f2 = -0.5f * (ax - 1.0f) * t * t;
    return ax <= 1.0f ? f1 : (ax < 2.0f ? f2 : 0.0f);
}

__device__ __forceinline__ float u_of_j(int j) {
    const float c0 = -0.5f / 0.05f;                        // k_in[0] = -10
    const float c1 = (-0.5f + 1.0f / 1023.0f) / 0.05f;     // k_in[1]
    const float h  = c1 - c0;
    float kout = (-0.5f + (float)j * (1.0f / 1535.0f)) / 0.15f;
    return (kout - c0) / h;                                // in [341, 682]
}

// One block: output tile [y0..y0+5] x [X0..X0+255] x 4 channels.
// Thread: 1 channel x 4 cols x 6 rows.
__global__ __launch_bounds__(256)
void fused_lds(const float* __restrict__ re, float* __restrict__ out) {
    const int tid = threadIdx.x;
    const int X0  = blockIdx.x * XT;
    const int y0  = blockIdx.y * TY;
    const int c0  = blockIdx.z * CPB;
    const int jx0 = X0 < 768 ? X0 + 768 : X0 - 768;   // contiguous over tile
    const int jy0 = y0 < 768 ? y0 + 768 : y0 - 768;

    // x stage window: covers all taps of the 256 output cols
    int stage_b = (int)floorf(u_of_j(jx0)) - 1;
    stage_b = min(max(stage_b, 0), N_IN_ - XW);
    // y input window: 6 rows cover all taps of the 6 output rows
    int byb = (int)floorf(u_of_j(jy0)) - 1;
    byb = min(max(byb, 0), N_IN_ - TY);

    __shared__ float lds[CPB][TY][XW];

    // ---- stage 4ch x 6rows x 64cols = 6 KB ----
    // fftshift cols: window contiguous in memory unless it straddles idx 512.
    const bool hi = (stage_b >= 512);
    const bool lo = (stage_b + XW <= 512);
    if (hi || lo) {
        const int xbase = hi ? (stage_b - 512) : (stage_b + 512);
        #pragma unroll
        for (int it = 0; it < 2; ++it) {
            const int task = it * 256 + tid;          // 384 float4 tasks
            if (task < CPB * TY * (XW / 4)) {
                const int pr  = task >> 4;            // (ch,row) pair 0..23
                const int e   = task & 15;            // float4 index in row
                const int ch  = pr / TY;
                const int row = pr - ch * TY;
                const int r   = byb + row;
                const int rm  = (r >= 512) ? (r - 512) : (r + 512);
                float4 v;
                __builtin_memcpy(&v,
                    re + (size_t)(c0 + ch) * (N_IN_ * N_IN_)
                       + (size_t)rm * N_IN_ + xbase + 4 * e, 16);
                *(float4*)&lds[ch][row][4 * e] = v;
            }
        }
    } else {
        // straddling window (2 of 6 x-tiles): per-element gather
        const int e = tid & 63;
        const int t = stage_b + e;
        const int cmem = (t >= 512) ? (t - 512) : (t + 512);
        #pragma unroll
        for (int s = 0; s < CPB * TY / 4; ++s) {
            const int pr  = s * 4 + (tid >> 6);
            const int ch  = pr / TY;
            const int row = pr - ch * TY;
            const int r   = byb + row;
            const int rm  = (r >= 512) ? (r - 512) : (r + 512);
            lds[ch][row][e] =
                re[(size_t)(c0 + ch) * (N_IN_ * N_IN_) + (size_t)rm * N_IN_ + cmem];
        }
    }

    // ---- weights (overlap with staging latency) ----
    // y 6x6 matrix, block-uniform; RES_RATIO=3 folded here.
    float wmat[TY][TY];
    #pragma unroll
    for (int i = 0; i < TY; ++i) {
        float ui = u_of_j(jy0 + i);
        #pragma unroll
        for (int j = 0; j < TY; ++j)
            wmat[i][j] = 3.0f * cubic_w(ui - (float)(byb + j));
    }

    // per-thread: 4 consecutive output cols, one shared 6-wide x window
    const int xq  = tid & 63;       // col-quad 0..63
    const int cg  = tid >> 6;       // channel within block (wave-uniform)
    const int x0l = xq * 4;
    float wx6[4][6];
    int w0;
    {
        float u0 = u_of_j(jx0 + x0l);
        w0 = (int)floorf(u0) - 1 - stage_b;       // 0..57
        w0 = min(max(w0, 0), XW - 6);
        #pragma unroll
        for (int k = 0; k < 4; ++k) {
            float uk = u_of_j(jx0 + x0l + k);
            #pragma unroll
            for (int j = 0; j < 6; ++j)
                wx6[k][j] = cubic_w(uk - (float)(stage_b + w0 + j));
        }
    }

    __syncthreads();

    const int c = c0 + cg;
    float acc[TY][4];
    #pragma unroll
    for (int i = 0; i < TY; ++i)
        #pragma unroll
        for (int k = 0; k < 4; ++k) acc[i][k] = 0.0f;

    #pragma unroll
    for (int j = 0; j < TY; ++j) {
        const float* p = &lds[cg][j][w0];
        const float L0 = p[0], L1 = p[1], L2 = p[2],
                    L3 = p[3], L4 = p[4], L5 = p[5];
        float xr0, xr1, xr2, xr3;
        xr0 = fmaf(wx6[0][5], L5, fmaf(wx6[0][4], L4, fmaf(wx6[0][3], L3,
              fmaf(wx6[0][2], L2, fmaf(wx6[0][1], L1, wx6[0][0] * L0)))));
        xr1 = fmaf(wx6[1][5], L5, fmaf(wx6[1][4], L4, fmaf(wx6[1][3], L3,
              fmaf(wx6[1][2], L2, fmaf(wx6[1][1], L1, wx6[1][0] * L0)))));
        xr2 = fmaf(wx6[2][5], L5, fmaf(wx6[2][4], L4, fmaf(wx6[2][3], L3,
              fmaf(wx6[2][2], L2, fmaf(wx6[2][1], L1, wx6[2][0] * L0)))));
        xr3 = fmaf(wx6[3][5], L5, fmaf(wx6[3][4], L4, fmaf(wx6[3][3], L3,
              fmaf(wx6[3][2], L2, fmaf(wx6[3][1], L1, wx6[3][0] * L0)))));
        #pragma unroll
        for (int i = 0; i < TY; ++i) {
            const float w = wmat[i][j];
            acc[i][0] = fmaf(w, xr0, acc[i][0]);
            acc[i][1] = fmaf(w, xr1, acc[i][1]);
            acc[i][2] = fmaf(w, xr2, acc[i][2]);
            acc[i][3] = fmaf(w, xr3, acc[i][3]);
        }
    }

    float* ob = out + (size_t)c * (N_OUT_ * N_OUT_)
                    + (size_t)y0 * N_OUT_ + X0 + x0l;
    #pragma unroll
    for (int i = 0; i < TY; ++i) {
        float4 a = make_float4(acc[i][0], acc[i][1], acc[i][2], acc[i][3]);
        *(float4*)(ob + (size_t)i * N_OUT_) = a;
    }
}

// ---------------- Defensive: complex-interleaved output variant --------------
__global__ __launch_bounds__(256)
void resample_cplx(const float* __restrict__ re,
                   const float* __restrict__ im,
                   float2* __restrict__ out) {
    const int x = blockIdx.x * 256 + threadIdx.x;
    const int y = blockIdx.y;
    const int jx = x < 768 ? x + 768 : x - 768;
    const int jy = y < 768 ? y + 768 : y - 768;

    float ux = u_of_j(jx), uy = u_of_j(jy);
    int bx = min(max((int)floorf(ux) - 1, 0), N_IN_ - 4);
    int by = min(max((int)floorf(uy) - 1, 0), N_IN_ - 4);
    float wx[4], wy[4];
    #pragma unroll
    for (int d = 0; d < 4; ++d) {
        wx[d] = cubic_w(ux - (float)(bx + d));
        wy[d] = 3.0f * cubic_w(uy - (float)(by + d));
    }
    float w[4][4];
    #pragma unroll
    for (int dy = 0; dy < 4; ++dy)
        #pragma unroll
        for (int dx = 0; dx < 4; ++dx) w[dy][dx] = wy[dy] * wx[dx];

    int rofs[4];
    #pragma unroll
    for (int dy = 0; dy < 4; ++dy) {
        int t = by + dy;
        rofs[dy] = ((t >= 512) ? (t - 512) : (t + 512)) * N_IN_;
    }
    int cm[4];
    #pragma unroll
    for (int d = 0; d < 4; ++d) {
        int t = bx + d;
        cm[d] = (t >= 512) ? (t - 512) : (t + 512);
    }

    const int outbase = y * N_OUT_ + x;
    for (int c = 0; c < N_CH; ++c) {
        const float* rec = re + (size_t)c * (N_IN_ * N_IN_);
        const float* imc = im + (size_t)c * (N_IN_ * N_IN_);
        float ar = 0.0f, ai = 0.0f;
        #pragma unroll
        for (int dy = 0; dy < 4; ++dy) {
            #pragma unroll
            for (int d = 0; d < 4; ++d) {
                ar = fmaf(w[dy][d], rec[rofs[dy] + cm[d]], ar);
                ai = fmaf(w[dy][d], imc[rofs[dy] + cm[d]], ai);
            }
        }
        out[(size_t)c * (N_OUT_ * N_OUT_) + outbase] = make_float2(ar, ai);
    }
}

extern "C" void kernel_launch(void* const* d_in, const int* in_sizes, int n_in,
                              void* d_out, int out_size, void* d_ws, size_t ws_size,
                              hipStream_t stream) {
    const float* re = (const float*)d_in[0];   // kimage_real (16,1024,1024)
    const float* im = (const float*)d_in[1];   // kimage_imag (16,1024,1024)

    if (out_size >= 2 * N_CH * N_OUT_ * N_OUT_) {
        // complex-interleaved output (defensive; not the observed case)
        resample_cplx<<<dim3(N_OUT_ / 256, N_OUT_), dim3(256), 0, stream>>>(
            re, im, (float2*)d_out);
    } else {
        fused_lds<<<dim3(N_OUT_ / XT, N_OUT_ / TY, N_CH / CPB),
                    dim3(256), 0, stream>>>(re, (float*)d_out);
    }
}

// Round 8
// 38.905 us; speedup vs baseline: 1.3357x; 1.3357x over previous
//
#include <hip/hip_runtime.h>

#define N_IN_   1024
#define N_OUT_  1536
#define N_CH    16
#define TY      6       // output rows per block tile (6 | 768: never straddles ifftshift wrap)
#define XT      256     // output cols per block tile (256 | 768)
#define XW      64      // staged input x-window (max span 61 < 64)

typedef float f4_t __attribute__((ext_vector_type(4)));

// Catmull-Rom-style cubic kernel, matching the reference formula in f32.
// Exact 0 for |x| >= 2 -> widened tap windows are formula-identical.
__device__ __forceinline__ float cubic_w(float x) {
    float ax = fabsf(x);
    float f1 = 1.0f + ax * ax * (1.5f * ax - 2.5f);
    float t  = 2.0f - ax;
    float f2 = -0.5f * (ax - 1.0f) * t * t;
    return ax <= 1.0f ? f1 : (ax < 2.0f ? f2 : 0.0f);
}

__device__ __forceinline__ float u_of_j(int j) {
    const float c0 = -0.5f / 0.05f;                        // k_in[0] = -10
    const float c1 = (-0.5f + 1.0f / 1023.0f) / 0.05f;     // k_in[1]
    const float h  = c1 - c0;
    float kout = (-0.5f + (float)j * (1.0f / 1535.0f)) / 0.15f;
    return (kout - c0) / h;                                // in [341, 682]
}

// One block: output tile [y0..y0+5] x [X0..X0+255] x all 16 channels.
// Wave w stages AND computes channels 4w..4w+3. Thread: 4 ch x 4 cols x 6 rows.
__global__ __launch_bounds__(256)
void fused_lds(const float* __restrict__ re, float* __restrict__ out) {
    const int tid = threadIdx.x;
    const int wv  = tid >> 6;       // wave 0..3
    const int ln  = tid & 63;       // lane
    const int X0  = blockIdx.x * XT;
    const int y0  = blockIdx.y * TY;
    const int jx0 = X0 < 768 ? X0 + 768 : X0 - 768;   // contiguous over tile
    const int jy0 = y0 < 768 ? y0 + 768 : y0 - 768;

    // x stage window: covers all taps of the 256 output cols
    int stage_b = (int)floorf(u_of_j(jx0)) - 1;
    stage_b = min(max(stage_b, 0), N_IN_ - XW);
    // y input window: 6 rows cover all taps of the 6 output rows
    int byb = (int)floorf(u_of_j(jy0)) - 1;
    byb = min(max(byb, 0), N_IN_ - TY);

    __shared__ float lds[N_CH][TY][XW];

    // y row -> fftshifted memory row offset (block-uniform)
    int rmofs[TY];
    #pragma unroll
    for (int j = 0; j < TY; ++j) {
        int r = byb + j;
        rmofs[j] = ((r >= 512) ? (r - 512) : (r + 512)) * N_IN_;
    }

    // ---- stage: wave-local, 4ch x 6rows x 64cols = 6 KB per wave ----
    const bool hi = (stage_b >= 512);
    const bool lo = (stage_b + XW <= 512);
    if (hi || lo) {
        const int xbase = hi ? (stage_b - 512) : (stage_b + 512);
        #pragma unroll
        for (int k = 0; k < 6; ++k) {
            const int t   = k * 64 + ln;          // 0..383 within wave
            const int ch  = t / 96;               // 0..3 (local)
            const int rem = t - ch * 96;
            const int row = rem >> 4;             // 0..5
            const int q   = rem & 15;             // float4 index in row
            const int c   = 4 * wv + ch;
            f4_t v;
            __builtin_memcpy(&v,
                re + (size_t)c * (N_IN_ * N_IN_) + rmofs[row] + xbase + 4 * q, 16);
            *(f4_t*)&lds[c][row][4 * q] = v;
        }
    } else {
        // straddling window (2 of 6 x-tiles): per-element gather, wave-local
        const int t = stage_b + ln;
        const int cmem = (t >= 512) ? (t - 512) : (t + 512);
        #pragma unroll
        for (int s = 0; s < 4 * TY; ++s) {
            const int ch  = s / TY;               // 0..3 (local)
            const int row = s - ch * TY;
            const int c   = 4 * wv + ch;
            lds[c][row][ln] =
                re[(size_t)c * (N_IN_ * N_IN_) + rmofs[row] + cmem];
        }
    }

    // ---- weights (overlap staging latency) ----
    // y 6x6 matrix, block-uniform; RES_RATIO=3 folded here.
    float wmat[TY][TY];
    #pragma unroll
    for (int i = 0; i < TY; ++i) {
        float ui = u_of_j(jy0 + i);
        #pragma unroll
        for (int j = 0; j < TY; ++j)
            wmat[i][j] = 3.0f * cubic_w(ui - (float)(byb + j));
    }

    // per-thread: 4 consecutive output cols, one shared 6-wide x window
    const int x0l = ln * 4;
    float wx6[4][6];
    int w0;
    {
        float u0 = u_of_j(jx0 + x0l);
        w0 = (int)floorf(u0) - 1 - stage_b;       // 0..57
        w0 = min(max(w0, 0), XW - 6);
        #pragma unroll
        for (int k = 0; k < 4; ++k) {
            float uk = u_of_j(jx0 + x0l + k);
            #pragma unroll
            for (int j = 0; j < 6; ++j)
                wx6[k][j] = cubic_w(uk - (float)(stage_b + w0 + j));
        }
    }

    __syncthreads();

    #pragma unroll
    for (int cc = 0; cc < 4; ++cc) {
        const int c = 4 * wv + cc;
        float acc[TY][4];
        #pragma unroll
        for (int i = 0; i < TY; ++i)
            #pragma unroll
            for (int k = 0; k < 4; ++k) acc[i][k] = 0.0f;

        #pragma unroll
        for (int j = 0; j < TY; ++j) {
            const float* p = &lds[c][j][w0];
            const float L0 = p[0], L1 = p[1], L2 = p[2],
                        L3 = p[3], L4 = p[4], L5 = p[5];
            float xr0, xr1, xr2, xr3;
            xr0 = fmaf(wx6[0][5], L5, fmaf(wx6[0][4], L4, fmaf(wx6[0][3], L3,
                  fmaf(wx6[0][2], L2, fmaf(wx6[0][1], L1, wx6[0][0] * L0)))));
            xr1 = fmaf(wx6[1][5], L5, fmaf(wx6[1][4], L4, fmaf(wx6[1][3], L3,
                  fmaf(wx6[1][2], L2, fmaf(wx6[1][1], L1, wx6[1][0] * L0)))));
            xr2 = fmaf(wx6[2][5], L5, fmaf(wx6[2][4], L4, fmaf(wx6[2][3], L3,
                  fmaf(wx6[2][2], L2, fmaf(wx6[2][1], L1, wx6[2][0] * L0)))));
            xr3 = fmaf(wx6[3][5], L5, fmaf(wx6[3][4], L4, fmaf(wx6[3][3], L3,
                  fmaf(wx6[3][2], L2, fmaf(wx6[3][1], L1, wx6[3][0] * L0)))));
            #pragma unroll
            for (int i = 0; i < TY; ++i) {
                const float w = wmat[i][j];
                acc[i][0] = fmaf(w, xr0, acc[i][0]);
                acc[i][1] = fmaf(w, xr1, acc[i][1]);
                acc[i][2] = fmaf(w, xr2, acc[i][2]);
                acc[i][3] = fmaf(w, xr3, acc[i][3]);
            }
        }

        float* ob = out + (size_t)c * (N_OUT_ * N_OUT_)
                        + (size_t)y0 * N_OUT_ + X0 + x0l;
        #pragma unroll
        for (int i = 0; i < TY; ++i) {
            f4_t a = { acc[i][0], acc[i][1], acc[i][2], acc[i][3] };
            __builtin_nontemporal_store(a, (f4_t*)(ob + (size_t)i * N_OUT_));
        }
    }
}

// ---------------- Defensive: complex-interleaved output variant --------------
__global__ __launch_bounds__(256)
void resample_cplx(const float* __restrict__ re,
                   const float* __restrict__ im,
                   float2* __restrict__ out) {
    const int x = blockIdx.x * 256 + threadIdx.x;
    const int y = blockIdx.y;
    const int jx = x < 768 ? x + 768 : x - 768;
    const int jy = y < 768 ? y + 768 : y - 768;

    float ux = u_of_j(jx), uy = u_of_j(jy);
    int bx = min(max((int)floorf(ux) - 1, 0), N_IN_ - 4);
    int by = min(max((int)floorf(uy) - 1, 0), N_IN_ - 4);
    float wx[4], wy[4];
    #pragma unroll
    for (int d = 0; d < 4; ++d) {
        wx[d] = cubic_w(ux - (float)(bx + d));
        wy[d] = 3.0f * cubic_w(uy - (float)(by + d));
    }
    float w[4][4];
    #pragma unroll
    for (int dy = 0; dy < 4; ++dy)
        #pragma unroll
        for (int dx = 0; dx < 4; ++dx) w[dy][dx] = wy[dy] * wx[dx];

    int rofs[4];
    #pragma unroll
    for (int dy = 0; dy < 4; ++dy) {
        int t = by + dy;
        rofs[dy] = ((t >= 512) ? (t - 512) : (t + 512)) * N_IN_;
    }
    int cm[4];
    #pragma unroll
    for (int d = 0; d < 4; ++d) {
        int t = bx + d;
        cm[d] = (t >= 512) ? (t - 512) : (t + 512);
    }

    const int outbase = y * N_OUT_ + x;
    for (int c = 0; c < N_CH; ++c) {
        const float* rec = re + (size_t)c * (N_IN_ * N_IN_);
        const float* imc = im + (size_t)c * (N_IN_ * N_IN_);
        float ar = 0.0f, ai = 0.0f;
        #pragma unroll
        for (int dy = 0; dy < 4; ++dy) {
            #pragma unroll
            for (int d = 0; d < 4; ++d) {
                ar = fmaf(w[dy][d], rec[rofs[dy] + cm[d]], ar);
                ai = fmaf(w[dy][d], imc[rofs[dy] + cm[d]], ai);
            }
        }
        out[(size_t)c * (N_OUT_ * N_OUT_) + outbase] = make_float2(ar, ai);
    }
}

extern "C" void kernel_launch(void* const* d_in, const int* in_sizes, int n_in,
                              void* d_out, int out_size, void* d_ws, size_t ws_size,
                              hipStream_t stream) {
    const float* re = (const float*)d_in[0];   // kimage_real (16,1024,1024)
    const float* im = (const float*)d_in[1];   // kimage_imag (16,1024,1024)

    if (out_size >= 2 * N_CH * N_OUT_ * N_OUT_) {
        // complex-interleaved output (defensive; not the observed case)
        resample_cplx<<<dim3(N_OUT_ / 256, N_OUT_), dim3(256), 0, stream>>>(
            re, im, (float2*)d_out);
    } else {
        fused_lds<<<dim3(N_OUT_ / XT, N_OUT_ / TY), dim3(256), 0, stream>>>(
            re, (float*)d_out);
    }
}